// Round 3
// baseline (517.369 us; speedup 1.0000x reference)
//
#include <hip/hip_runtime.h>
#include <math.h>

#define T_TOTAL 16384
#define HDIM    2048
#define NEXP    64

// ---------------------------------------------------------------------------
// Scalar-pipe GEMM: thread = 1 token, X row slice in VGPRs, W rows fetched
// via s_load (wave-uniform addresses -> scalar pipe / K$), VALU does pure FMA.
//   partial[t][ks][e] = sum_{k in slice ks} x[t][k] * w[e][k]
// Block: 256 threads = 256 tokens. Grid: 64 token-blocks x KS k-slices.
// ---------------------------------------------------------------------------
template<int KS>
__global__ __launch_bounds__(256)
void router_gemm_kernel(const float* __restrict__ x,
                        const float* __restrict__ w,
                        float* __restrict__ partial)
{
    constexpr int KSLICE = HDIM / KS;          // 64 (KS=32) or 128 (KS=16)

    const int tid = threadIdx.x;
    const int tb  = blockIdx.x & 63;           // token block
    const int ks  = blockIdx.x >> 6;           // k-slice
    const int t   = tb * 256 + tid;
    const int k0  = ks * KSLICE;

    // Load this token's k-slice into registers (once; reused for all 64 experts).
    float xr[KSLICE];
    {
        const float* xp = x + (size_t)t * HDIM + k0;
#pragma unroll
        for (int q = 0; q < KSLICE / 4; ++q) {
            const float4 v = *(const float4*)(xp + q * 4);
            xr[q * 4 + 0] = v.x;
            xr[q * 4 + 1] = v.y;
            xr[q * 4 + 2] = v.z;
            xr[q * 4 + 3] = v.w;
        }
    }

    float* pout = partial + ((size_t)t * KS + ks) * NEXP;

    // Expert groups of 4: inner k fully unrolled; w indexed only by uniform
    // (blockIdx / loop-constant) offsets -> compiler emits s_load_dwordx16,
    // keeping the vector pipe ~100% FMA.
#pragma unroll 1
    for (int e4 = 0; e4 < NEXP; e4 += 4) {
        const float* __restrict__ w0 = w + (size_t)(e4 + 0) * HDIM + k0;
        const float* __restrict__ w1 = w + (size_t)(e4 + 1) * HDIM + k0;
        const float* __restrict__ w2 = w + (size_t)(e4 + 2) * HDIM + k0;
        const float* __restrict__ w3 = w + (size_t)(e4 + 3) * HDIM + k0;

        float a0 = 0.0f, a1 = 0.0f, a2 = 0.0f, a3 = 0.0f;
#pragma unroll
        for (int k = 0; k < KSLICE; ++k) {
            const float xv = xr[k];
            a0 = fmaf(xv, w0[k], a0);
            a1 = fmaf(xv, w1[k], a1);
            a2 = fmaf(xv, w2[k], a2);
            a3 = fmaf(xv, w3[k], a3);
        }
        *(float4*)(pout + e4) = make_float4(a0, a1, a2, a3);
    }
}

// ---------------------------------------------------------------------------
// Sum KS partials + sigmoid + biased top-8 (desc, ties -> lower idx) +
// renorm * 2.5. One wave per token, lane = expert.
// ---------------------------------------------------------------------------
__global__ __launch_bounds__(256)
void router_topk_kernel(const float* __restrict__ partial,
                        const float* __restrict__ bias,
                        float* __restrict__ out_scores,
                        float* __restrict__ out_idx,
                        int ksCount)
{
    const int token = blockIdx.x * 4 + (threadIdx.x >> 6);
    const int lane  = threadIdx.x & 63;

    const float* pt = partial + (size_t)token * ksCount * NEXP + lane;
    float logit = 0.0f;
    for (int s = 0; s < ksCount; ++s) logit += pt[(size_t)s * NEXP];

    const float score = 1.0f / (1.0f + expf(-logit));
    float key = score + bias[lane];

    float myscore = 0.0f;
    int   myidx   = 0;
    float denom   = 0.0f;

#pragma unroll
    for (int r = 0; r < 8; ++r) {
        float bk = key;
        int   bi = lane;
#pragma unroll
        for (int off = 32; off > 0; off >>= 1) {
            const float ok = __shfl_xor(bk, off);
            const int   oi = __shfl_xor(bi, off);
            if (ok > bk || (ok == bk && oi < bi)) { bk = ok; bi = oi; }
        }
        const float wsc = __shfl(score, bi);   // raw (unbiased) winner score
        denom += wsc;
        if (lane == r)  { myscore = wsc; myidx = bi; }
        if (lane == bi) key = -__builtin_inff();
    }

    const float factor = 2.5f / (denom + 1e-20f);
    if (lane < 8) {
        out_scores[(size_t)token * 8 + lane] = myscore * factor;
        out_idx  [(size_t)token * 8 + lane] = (float)myidx;
    }
}

// ---------------------------------------------------------------------------
extern "C" void kernel_launch(void* const* d_in, const int* in_sizes, int n_in,
                              void* d_out, int out_size, void* d_ws, size_t ws_size,
                              hipStream_t stream)
{
    const float* x    = (const float*)d_in[0];   // [4,4096,2048] f32
    const float* bias = (const float*)d_in[1];   // [64] f32
    const float* w    = (const float*)d_in[2];   // [64,2048] f32

    float* out     = (float*)d_out;
    float* partial = (float*)d_ws;

    const size_t bytesPerSlice = (size_t)T_TOTAL * NEXP * 4;   // 4 MiB

    int ksCount;
    if (ws_size >= 33 * bytesPerSlice) {         // 128 MiB + margin
        ksCount = 32;
        router_gemm_kernel<32><<<dim3(64 * 32), dim3(256), 0, stream>>>(x, w, partial);
    } else {                                     // 64 MiB confirmed available
        ksCount = 16;
        router_gemm_kernel<16><<<dim3(64 * 16), dim3(256), 0, stream>>>(x, w, partial);
    }

    router_topk_kernel<<<dim3(T_TOTAL / 4), dim3(256), 0, stream>>>(
        partial, bias, out, out + (size_t)T_TOTAL * 8, ksCount);
}

// Round 4
// 251.781 us; speedup vs baseline: 2.0548x; 2.0548x over previous
//
#include <hip/hip_runtime.h>
#include <math.h>

#define T_TOTAL 16384
#define HDIM    2048
#define NEXP    64

// ---------------------------------------------------------------------------
// LDS-tiled register GEMM (round-1 structure, occupancy+conflict fixed):
//   partial[t][ks][e] = sum_{k in slice ks} x[t][k] * w[e][k]
// Block: 256 threads, 256 tokens x 64 experts; thread: 8x8 acc tile.
// KS=16 -> grid 1024 (4 blocks/CU); BK=16 -> LDS 20.3 KB (not occupancy-
// limiting); strides 258/66 (== 2 mod 32) -> transpose staging writes are
// exactly 2-way bank-aliased = free (m136).
// ---------------------------------------------------------------------------
template<int KS>
__global__ __launch_bounds__(256, 4)
void router_gemm_kernel(const float* __restrict__ x,
                        const float* __restrict__ w,
                        float* __restrict__ partial)
{
    constexpr int KSLICE = HDIM / KS;   // 128 for KS=16
    constexpr int BK    = 16;
    constexpr int XS_ST = 258;          // 256 tokens + 2 pad
    constexpr int WS_ST = 66;           // 64 experts + 2 pad

    __shared__ float Xs[BK][XS_ST];     // [k][token]
    __shared__ float Ws[BK][WS_ST];     // [k][expert]

    const int tid = threadIdx.x;
    const int tb  = blockIdx.x & 63;    // token block (64 x 256 tokens)
    const int ks  = blockIdx.x >> 6;    // k-slice
    const int t0  = tb * 256;
    const int k0  = ks * KSLICE;

    const int kq  = tid & 3;            // staging k-quad (kq*4 .. +3)
    const int rr  = tid >> 2;           // staging row 0..63

    const int eg8 = (tid & 7) * 8;      // this thread's 8 experts
    const int tg8 = (tid >> 3) * 8;     // this thread's 8 tokens

    float acc[8][8];
#pragma unroll
    for (int i = 0; i < 8; ++i)
#pragma unroll
        for (int j = 0; j < 8; ++j) acc[i][j] = 0.0f;

#pragma unroll 1
    for (int kc = 0; kc < KSLICE; kc += BK) {
        __syncthreads();

        // stage X tile: 256 tokens x 16 k, transposed -> [k][token]
        {
            const float* xg = x + (size_t)t0 * HDIM + (k0 + kc) + kq * 4;
#pragma unroll
            for (int p = 0; p < 4; ++p) {
                const int r = p * 64 + rr;
                const float4 v = *(const float4*)(xg + (size_t)r * HDIM);
                Xs[kq * 4 + 0][r] = v.x;
                Xs[kq * 4 + 1][r] = v.y;
                Xs[kq * 4 + 2][r] = v.z;
                Xs[kq * 4 + 3][r] = v.w;
            }
        }
        // stage W tile: 64 experts x 16 k, transposed -> [k][expert]
        {
            const float4 v = *(const float4*)(w + (size_t)rr * HDIM + (k0 + kc) + kq * 4);
            Ws[kq * 4 + 0][rr] = v.x;
            Ws[kq * 4 + 1][rr] = v.y;
            Ws[kq * 4 + 2][rr] = v.z;
            Ws[kq * 4 + 3][rr] = v.w;
        }
        __syncthreads();

#pragma unroll
        for (int k = 0; k < BK; ++k) {
            float xv[8], wv[8];
#pragma unroll
            for (int i = 0; i < 8; ++i) xv[i] = Xs[k][tg8 + i];
#pragma unroll
            for (int j = 0; j < 8; ++j) wv[j] = Ws[k][eg8 + j];
#pragma unroll
            for (int i = 0; i < 8; ++i)
#pragma unroll
                for (int j = 0; j < 8; ++j)
                    acc[i][j] = fmaf(xv[i], wv[j], acc[i][j]);
        }
    }

    // write partial [t][ks][e] -> top-k reads each token contiguously
    float* pp = partial + ((size_t)(t0 + tg8) * KS + ks) * NEXP + eg8;
#pragma unroll
    for (int i = 0; i < 8; ++i) {
        float* q = pp + (size_t)i * KS * NEXP;
        *(float4*)(q)     = make_float4(acc[i][0], acc[i][1], acc[i][2], acc[i][3]);
        *(float4*)(q + 4) = make_float4(acc[i][4], acc[i][5], acc[i][6], acc[i][7]);
    }
}

// ---------------------------------------------------------------------------
// Sum KS partials + sigmoid + biased top-8 (desc, ties -> lower idx) +
// renorm * 2.5. One wave per token, lane = expert.
// ---------------------------------------------------------------------------
__global__ __launch_bounds__(256)
void router_topk_kernel(const float* __restrict__ partial,
                        const float* __restrict__ bias,
                        float* __restrict__ out_scores,
                        float* __restrict__ out_idx,
                        int ksCount)
{
    const int token = blockIdx.x * 4 + (threadIdx.x >> 6);
    const int lane  = threadIdx.x & 63;

    const float* pt = partial + (size_t)token * ksCount * NEXP + lane;
    float logit = 0.0f;
    for (int s = 0; s < ksCount; ++s) logit += pt[(size_t)s * NEXP];

    const float score = 1.0f / (1.0f + expf(-logit));
    float key = score + bias[lane];

    float myscore = 0.0f;
    int   myidx   = 0;
    float denom   = 0.0f;

#pragma unroll
    for (int r = 0; r < 8; ++r) {
        float bk = key;
        int   bi = lane;
#pragma unroll
        for (int off = 32; off > 0; off >>= 1) {
            const float ok = __shfl_xor(bk, off);
            const int   oi = __shfl_xor(bi, off);
            if (ok > bk || (ok == bk && oi < bi)) { bk = ok; bi = oi; }
        }
        const float wsc = __shfl(score, bi);   // raw (unbiased) winner score
        denom += wsc;
        if (lane == r)  { myscore = wsc; myidx = bi; }
        if (lane == bi) key = -__builtin_inff();
    }

    const float factor = 2.5f / (denom + 1e-20f);
    if (lane < 8) {
        out_scores[(size_t)token * 8 + lane] = myscore * factor;
        out_idx  [(size_t)token * 8 + lane] = (float)myidx;
    }
}

// ---------------------------------------------------------------------------
extern "C" void kernel_launch(void* const* d_in, const int* in_sizes, int n_in,
                              void* d_out, int out_size, void* d_ws, size_t ws_size,
                              hipStream_t stream)
{
    const float* x    = (const float*)d_in[0];   // [4,4096,2048] f32
    const float* bias = (const float*)d_in[1];   // [64] f32
    const float* w    = (const float*)d_in[2];   // [64,2048] f32

    float* out     = (float*)d_out;
    float* partial = (float*)d_ws;

    const size_t bytesPerSlice = (size_t)T_TOTAL * NEXP * 4;   // 4 MiB

    int ksCount;
    if (ws_size >= 16 * bytesPerSlice) {         // 64 MiB (confirmed available R2)
        ksCount = 16;
        router_gemm_kernel<16><<<dim3(64 * 16), dim3(256), 0, stream>>>(x, w, partial);
    } else {                                     // safety fallback
        ksCount = 4;
        router_gemm_kernel<4><<<dim3(64 * 4), dim3(256), 0, stream>>>(x, w, partial);
    }

    router_topk_kernel<<<dim3(T_TOTAL / 4), dim3(256), 0, stream>>>(
        partial, bias, out, out + (size_t)T_TOTAL * 8, ksCount);
}